// Round 2
// 386.849 us; speedup vs baseline: 1.0561x; 1.0561x over previous
//
#include <hip/hip_runtime.h>

// Problem constants: x (N=64, C=256, T=64, V=50) fp32; H=16; 10 parts.
#define N_  64
#define C_  256
#define T_  64
#define V_  50
#define H_  16
#define NP_ 10
#define ROW_ (T_ * V_)          // 3200 floats per (n,c) row
#define NC_  (N_ * C_)          // 16384 rows
#define NPC_ (N_ * NP_ * C_)    // 163840 floats per ws array

typedef float f32x4 __attribute__((ext_vector_type(4)));  // native vec for NT builtins

// part of each source vertex v (compile-time folded in unrolled loop)
constexpr int PART_OF_V[V_] = {
    0,0,0,0, 3,3,3,3, 1,1,1,1, 4,4,4,4, 2,2,2,2, 0, 3,3, 1,1,
    5,5,5,5, 8,8,8,8, 6,6,6,6, 9,9,9,9, 7,7,7,7, 5, 8,8, 6,6};

// 1 / (T * |part p|); sizes = {5,6,4,6,4,5,6,4,6,4}
constexpr float INV_CNT[NP_] = {
    1.f/320, 1.f/384, 1.f/256, 1.f/384, 1.f/256,
    1.f/320, 1.f/384, 1.f/256, 1.f/384, 1.f/256};

// out column w -> source v (concat of PARTS) and part of w (runtime-indexed)
__device__ const int SRC_V[V_] = {
    0,1,2,3,20,  8,9,10,11,23,24,  16,17,18,19,  4,5,6,7,21,22,  12,13,14,15,
    25,26,27,28,45,  33,34,35,36,48,49,  41,42,43,44,  29,30,31,32,46,47,  37,38,39,40};
__device__ const int PART_W[V_] = {
    0,0,0,0,0, 1,1,1,1,1,1, 2,2,2,2, 3,3,3,3,3,3, 4,4,4,4,
    5,5,5,5,5, 6,6,6,6,6,6, 7,7,7,7, 8,8,8,8,8,8, 9,9,9,9};

// ---------------------------------------------------------------------------
// Kernel A: per-(n,c) row, per-part sum & max over (T, V_p).
// One wave per row; 4 waves per block.  (unchanged — reads x, primes L3)
// ---------------------------------------------------------------------------
__global__ __launch_bounds__(256) void reduce_kernel(
    const float* __restrict__ x,
    float* __restrict__ avg_out,     // [(n*10+p)*256 + c]
    float* __restrict__ max_out) {
    __shared__ float lds[4][ROW_];
    const int wave = threadIdx.x >> 6;
    const int lane = threadIdx.x & 63;
    const int row  = blockIdx.x * 4 + wave;          // n*256 + c

    // coalesced float4 stage: 800 float4 per row
    const float4* xr4 = (const float4*)(x + (size_t)row * ROW_);
    float4* l4 = (float4*)lds[wave];
    #pragma unroll
    for (int j = 0; j < 12; ++j) l4[lane + 64 * j] = xr4[lane + 64 * j];
    if (lane < 32) l4[lane + 768] = xr4[lane + 768];
    __syncthreads();

    // lane == t; unrolled v loop, part index compile-time
    const float* l = lds[wave] + lane * V_;
    float s[NP_], m[NP_];
    #pragma unroll
    for (int p = 0; p < NP_; ++p) { s[p] = 0.f; m[p] = -__builtin_huge_valf(); }
    #pragma unroll
    for (int v = 0; v < V_; ++v) {
        float val = l[v];
        s[PART_OF_V[v]] += val;
        m[PART_OF_V[v]] = fmaxf(m[PART_OF_V[v]], val);
    }

    // butterfly over 64 lanes
    #pragma unroll
    for (int p = 0; p < NP_; ++p) {
        #pragma unroll
        for (int off = 32; off > 0; off >>= 1) {
            s[p] += __shfl_xor(s[p], off);
            m[p] = fmaxf(m[p], __shfl_xor(m[p], off));
        }
    }

    if (lane == 0) {
        const int n = row >> 8, c = row & 255;
        #pragma unroll
        for (int p = 0; p < NP_; ++p) {
            avg_out[(n * NP_ + p) * C_ + c] = s[p] * INV_CNT[p];
            max_out[(n * NP_ + p) * C_ + c] = m[p];
        }
    }
}

// ---------------------------------------------------------------------------
// Kernel B: gate[(n,p),c] = sigmoid( W2@(relu(W1@avg+b1)+relu(W1@mx+b1)) + 2*b2 )
// One block per (n,p); 256 threads.  (unchanged)
// ---------------------------------------------------------------------------
__global__ __launch_bounds__(256) void mlp_kernel(
    const float* __restrict__ avg, const float* __restrict__ mx,
    const float* __restrict__ W1, const float* __restrict__ b1,
    const float* __restrict__ W2, const float* __restrict__ b2,
    float* __restrict__ gate) {
    const int np = blockIdx.x;       // n*10 + p
    const int p  = np % NP_;
    __shared__ float vec[2][C_];
    __shared__ float partial[256];
    __shared__ float hsum[H_];

    const int t = threadIdx.x;
    vec[0][t] = avg[np * C_ + t];
    vec[1][t] = mx[np * C_ + t];
    __syncthreads();

    // partial dot: thread t = (chunk<<5) | (h<<1) | which ; 32 elements each
    const int which = t & 1, h = (t >> 1) & 15, chunk = t >> 5;
    const float* w1row = W1 + (p * H_ + h) * C_ + chunk * 32;
    const float* vv = vec[which] + chunk * 32;
    float acc = 0.f;
    #pragma unroll
    for (int k = 0; k < 32; ++k) acc += w1row[k] * vv[k];
    partial[t] = acc;
    __syncthreads();

    if (t < 32) {
        float a = b1[p * H_ + h];
        #pragma unroll
        for (int j = 0; j < 8; ++j) a += partial[t + 32 * j];
        a = fmaxf(a, 0.f);                       // relu
        if (which == 0) hsum[h] = a;
    }
    __syncthreads();
    if (t < 32 && (t & 1) == 1) {
        float a = b1[p * H_ + h];
        #pragma unroll
        for (int j = 0; j < 8; ++j) a += partial[t + 32 * j];
        hsum[h] += fmaxf(a, 0.f);
    }
    __syncthreads();

    // second layer: thread t = channel c
    const float4* w2row = (const float4*)(W2 + (p * C_ + t) * H_);
    float z = 2.f * b2[p * C_ + t];
    #pragma unroll
    for (int q = 0; q < 4; ++q) {
        float4 w = w2row[q];
        z += w.x * hsum[4*q] + w.y * hsum[4*q+1] + w.z * hsum[4*q+2] + w.w * hsum[4*q+3];
    }
    gate[np * C_ + t] = 1.f / (1.f + __expf(-z));
}

// ---------------------------------------------------------------------------
// Kernel C (v2, NT-store fix): permute + gate-multiply during STAGING.
//   - 50-entry packed LDS table tab[v] = {output column w (bitcast), gate(w)}
//     (SRC_V is a bijection on [0,50): wof[SRC_V[w]] = w.)
//   - Stage: coalesced float4 loads of x; each element scattered to its
//     OUTPUT flat position in LDS, premultiplied by its gate.
//   - Emit: pure contiguous ds_read_b128 + NON-TEMPORAL float4 store
//     (native ext_vector f32x4 — HIP float4 is rejected by the builtin).
//     NT stores keep x (209.7 MB < 256 MB L3) resident in Infinity Cache,
//     so this kernel's x read is an L3 hit -> write-bound floor ~33 us.
// ---------------------------------------------------------------------------
__device__ __forceinline__ void scatter4(float* __restrict__ ly,
                                         const float2* __restrict__ tab,
                                         int u, float4 d) {
    const int base = u * 4;
    int t = base / V_;
    int v = base - t * V_;           // source column of element 0
    float vals[4] = {d.x, d.y, d.z, d.w};
    #pragma unroll
    for (int k = 0; k < 4; ++k) {
        float2 tv = tab[v];          // {w bitcast to float, gate[w]}
        ly[t * V_ + __float_as_int(tv.x)] = vals[k] * tv.y;
        if (++v == V_) { v = 0; ++t; }
    }
}

__global__ __launch_bounds__(256) void scale_kernel(
    const float* __restrict__ x, const float* __restrict__ gate,
    float* __restrict__ out) {
    __shared__ float  ly[ROW_];      // 12.8 KB: permuted, gate-premultiplied row
    __shared__ float2 tab[V_];       // tab[src v] = {out col w, gate(w)}

    const int row = blockIdx.x;              // n*256 + c
    const int n = row >> 8, c = row & 255;
    const int tid = threadIdx.x;

    // ---- build permutation/gate table (50 threads)
    if (tid < V_) {
        const int w = tid;
        const int v = SRC_V[w];
        const float g = gate[(n * NP_ + PART_W[w]) * C_ + c];
        tab[v] = make_float2(__int_as_float(w), g);
    }

    // ---- issue all global loads for the row BEFORE the table barrier
    const float4* src = (const float4*)(x + (size_t)row * ROW_);
    float4 d0 = src[tid];
    float4 d1 = src[tid + 256];
    float4 d2 = src[tid + 512];
    float4 d3;
    if (tid < 32) d3 = src[tid + 768];
    __syncthreads();                 // tab ready

    // ---- scatter premultiplied values to output-ordered LDS positions
    scatter4(ly, tab, tid,       d0);
    scatter4(ly, tab, tid + 256, d1);
    scatter4(ly, tab, tid + 512, d2);
    if (tid < 32) scatter4(ly, tab, tid + 768, d3);
    __syncthreads();                 // ly complete

    // ---- emit: contiguous vector LDS reads + non-temporal coalesced stores
    const f32x4* ly4 = (const f32x4*)ly;
    f32x4* dst = (f32x4*)(out + (size_t)row * ROW_);
    __builtin_nontemporal_store(ly4[tid],       &dst[tid]);
    __builtin_nontemporal_store(ly4[tid + 256], &dst[tid + 256]);
    __builtin_nontemporal_store(ly4[tid + 512], &dst[tid + 512]);
    if (tid < 32)
        __builtin_nontemporal_store(ly4[tid + 768], &dst[tid + 768]);
}

// ---------------------------------------------------------------------------
extern "C" void kernel_launch(void* const* d_in, const int* in_sizes, int n_in,
                              void* d_out, int out_size, void* d_ws, size_t ws_size,
                              hipStream_t stream) {
    const float* x  = (const float*)d_in[0];
    const float* W1 = (const float*)d_in[1];
    const float* b1 = (const float*)d_in[2];
    const float* W2 = (const float*)d_in[3];
    const float* b2 = (const float*)d_in[4];
    float* out = (float*)d_out;

    float* avg  = (float*)d_ws;            // NPC_ floats
    float* mx   = avg + NPC_;              // NPC_ floats
    float* gate = mx + NPC_;               // NPC_ floats

    reduce_kernel<<<NC_ / 4, 256, 0, stream>>>(x, avg, mx);
    mlp_kernel<<<N_ * NP_, 256, 0, stream>>>(avg, mx, W1, b1, W2, b2, gate);
    scale_kernel<<<NC_, 256, 0, stream>>>(x, gate, out);
}

// Round 3
// 386.760 us; speedup vs baseline: 1.0564x; 1.0002x over previous
//
#include <hip/hip_runtime.h>

// Problem constants: x (N=64, C=256, T=64, V=50) fp32; H=16; 10 parts.
#define N_  64
#define C_  256
#define T_  64
#define V_  50
#define H_  16
#define NP_ 10
#define ROW_ (T_ * V_)          // 3200 floats per (n,c) row
#define NC_  (N_ * C_)          // 16384 rows
#define NPC_ (N_ * NP_ * C_)    // 163840 floats per ws array

typedef float f32x4 __attribute__((ext_vector_type(4)));  // native vec for NT builtins

// part of each source vertex v (compile-time folded in unrolled loop)
constexpr int PART_OF_V[V_] = {
    0,0,0,0, 3,3,3,3, 1,1,1,1, 4,4,4,4, 2,2,2,2, 0, 3,3, 1,1,
    5,5,5,5, 8,8,8,8, 6,6,6,6, 9,9,9,9, 7,7,7,7, 5, 8,8, 6,6};

// 1 / (T * |part p|); sizes = {5,6,4,6,4,5,6,4,6,4}  (runtime-indexed -> device global)
__device__ const float INV_CNT_D[NP_] = {
    1.f/320, 1.f/384, 1.f/256, 1.f/384, 1.f/256,
    1.f/320, 1.f/384, 1.f/256, 1.f/384, 1.f/256};

// out column w -> source v (concat of PARTS) and part of w (runtime-indexed)
__device__ const int SRC_V[V_] = {
    0,1,2,3,20,  8,9,10,11,23,24,  16,17,18,19,  4,5,6,7,21,22,  12,13,14,15,
    25,26,27,28,45,  33,34,35,36,48,49,  41,42,43,44,  29,30,31,32,46,47,  37,38,39,40};
__device__ const int PART_W[V_] = {
    0,0,0,0,0, 1,1,1,1,1,1, 2,2,2,2, 3,3,3,3,3,3, 4,4,4,4,
    5,5,5,5,5, 6,6,6,6,6,6, 7,7,7,7, 8,8,8,8,8,8, 9,9,9,9};

// ---------------------------------------------------------------------------
// Kernel A: per-(n,c) row, per-part sum & max over (T, V_p).
// One wave per row; 4 waves per block.
// v3: float2 accumulation reads; butterfly replaced by LDS transpose-reduce
// (20 dense stride-66 writes + 20-lane b64 reduction) — cuts LDS-pipe time
// from ~1330 to ~750 cyc/wave; 20 parallel output stores.
// ---------------------------------------------------------------------------
__global__ __launch_bounds__(256) void reduce_kernel(
    const float* __restrict__ x,
    float* __restrict__ avg_out,     // [(n*10+p)*256 + c]
    float* __restrict__ max_out) {
    __shared__ float lds[4][ROW_];
    const int wave = threadIdx.x >> 6;
    const int lane = threadIdx.x & 63;
    const int row  = blockIdx.x * 4 + wave;          // n*256 + c

    // coalesced float4 stage: 800 float4 per row
    const float4* xr4 = (const float4*)(x + (size_t)row * ROW_);
    float4* l4 = (float4*)lds[wave];
    #pragma unroll
    for (int j = 0; j < 12; ++j) l4[lane + 64 * j] = xr4[lane + 64 * j];
    if (lane < 32) l4[lane + 768] = xr4[lane + 768];
    __syncthreads();

    // lane == t; float2 reads (25 b64, ~optimal b64 bank pattern), part idx compile-time
    const float2* l2 = (const float2*)(lds[wave] + lane * V_);   // 200B offset, 8B aligned
    float s[NP_], m[NP_];
    #pragma unroll
    for (int p = 0; p < NP_; ++p) { s[p] = 0.f; m[p] = -__builtin_huge_valf(); }
    #pragma unroll
    for (int j = 0; j < 25; ++j) {
        float2 q = l2[j];
        s[PART_OF_V[2*j]]   += q.x;
        m[PART_OF_V[2*j]]    = fmaxf(m[PART_OF_V[2*j]], q.x);
        s[PART_OF_V[2*j+1]] += q.y;
        m[PART_OF_V[2*j+1]]  = fmaxf(m[PART_OF_V[2*j+1]], q.y);
    }

    // transpose-reduce in LDS (reuse this wave's staging region; 20*66=1320 < 3200)
    // buf[val][lane], val 0..9 = sums, 10..19 = maxes; stride 66 keeps b64 reads dense.
    float* buf = lds[wave];
    #pragma unroll
    for (int p = 0; p < NP_; ++p) {
        buf[p * 66 + lane]          = s[p];
        buf[(p + 10) * 66 + lane]   = m[p];
    }
    __syncthreads();

    if (lane < 20) {
        const int n = row >> 8, c = row & 255;
        const float2* b2 = (const float2*)(lds[wave] + lane * 66);  // 264B, 8B aligned
        if (lane < 10) {
            float2 a = b2[0];
            float acc = a.x + a.y;
            #pragma unroll
            for (int j = 1; j < 32; ++j) { float2 q = b2[j]; acc += q.x + q.y; }
            avg_out[(n * NP_ + lane) * C_ + c] = acc * INV_CNT_D[lane];
        } else {
            const int p = lane - 10;
            float2 a = b2[0];
            float acc = fmaxf(a.x, a.y);
            #pragma unroll
            for (int j = 1; j < 32; ++j) { float2 q = b2[j]; acc = fmaxf(acc, fmaxf(q.x, q.y)); }
            max_out[(n * NP_ + p) * C_ + c] = acc;
        }
    }
}

// ---------------------------------------------------------------------------
// Kernel B: gate[(n,p),c] = sigmoid( W2@(relu(W1@avg+b1)+relu(W1@mx+b1)) + 2*b2 )
// One block per (n,p); 256 threads.  (unchanged)
// ---------------------------------------------------------------------------
__global__ __launch_bounds__(256) void mlp_kernel(
    const float* __restrict__ avg, const float* __restrict__ mx,
    const float* __restrict__ W1, const float* __restrict__ b1,
    const float* __restrict__ W2, const float* __restrict__ b2,
    float* __restrict__ gate) {
    const int np = blockIdx.x;       // n*10 + p
    const int p  = np % NP_;
    __shared__ float vec[2][C_];
    __shared__ float partial[256];
    __shared__ float hsum[H_];

    const int t = threadIdx.x;
    vec[0][t] = avg[np * C_ + t];
    vec[1][t] = mx[np * C_ + t];
    __syncthreads();

    // partial dot: thread t = (chunk<<5) | (h<<1) | which ; 32 elements each
    const int which = t & 1, h = (t >> 1) & 15, chunk = t >> 5;
    const float* w1row = W1 + (p * H_ + h) * C_ + chunk * 32;
    const float* vv = vec[which] + chunk * 32;
    float acc = 0.f;
    #pragma unroll
    for (int k = 0; k < 32; ++k) acc += w1row[k] * vv[k];
    partial[t] = acc;
    __syncthreads();

    if (t < 32) {
        float a = b1[p * H_ + h];
        #pragma unroll
        for (int j = 0; j < 8; ++j) a += partial[t + 32 * j];
        a = fmaxf(a, 0.f);                       // relu
        if (which == 0) hsum[h] = a;
    }
    __syncthreads();
    if (t < 32 && (t & 1) == 1) {
        float a = b1[p * H_ + h];
        #pragma unroll
        for (int j = 0; j < 8; ++j) a += partial[t + 32 * j];
        hsum[h] += fmaxf(a, 0.f);
    }
    __syncthreads();

    // second layer: thread t = channel c
    const float4* w2row = (const float4*)(W2 + (p * C_ + t) * H_);
    float z = 2.f * b2[p * C_ + t];
    #pragma unroll
    for (int q = 0; q < 4; ++q) {
        float4 w = w2row[q];
        z += w.x * hsum[4*q] + w.y * hsum[4*q+1] + w.z * hsum[4*q+2] + w.w * hsum[4*q+3];
    }
    gate[np * C_ + t] = 1.f / (1.f + __expf(-z));
}

// ---------------------------------------------------------------------------
// Kernel C (v3): swizzled single-buffer stage + table-driven gather emit.
//   - lx staged with 4B-granularity XOR swizzle f ^= (f>>5)&3 : both the
//     dense stage writes AND the 16B-lane-stride gather reads hit ~all 32
//     banks (was 8-way conflict on the v2 scatter writes).
//   - 25-entry float4 LDS table tq[j] = {dsv(2j), gv(2j), dsv(2j+1), gv(2j+1)}
//     where dsv[w] = SRC_V[w]-w (so src flat = e + dsv[e%50]) and gv[w] =
//     gate for output column w. Two b128 table reads per output quad.
//   - Emit: 4 swizzled scalar LDS gathers + gate mul + NT float4 store
//     (NT keeps x resident in L3 for this second pass).
// ---------------------------------------------------------------------------
__global__ __launch_bounds__(256) void scale_kernel(
    const float* __restrict__ x, const float* __restrict__ gate,
    float* __restrict__ out) {
    __shared__ float  lx[ROW_];      // 12.8 KB swizzled staged row
    __shared__ float4 tq[25];        // packed {dsv,gv} pairs, indexed by w>>1

    const int row = blockIdx.x;              // n*256 + c
    const int n = row >> 8, c = row & 255;
    const int tid = threadIdx.x;

    // ---- build permutation/gate table (50 threads; component writes, no race)
    if (tid < V_) {
        const int w = tid;
        const float g = gate[(n * NP_ + PART_W[w]) * C_ + c];
        const int dsv = SRC_V[w] - w;
        float* t4 = (float*)&tq[w >> 1];
        t4[(w & 1) * 2 + 0] = __int_as_float(dsv);
        t4[(w & 1) * 2 + 1] = g;
    }

    // ---- issue all global loads for the row (coalesced float4)
    const float4* src = (const float4*)(x + (size_t)row * ROW_);
    float4 d0 = src[tid];
    float4 d1 = src[tid + 256];
    float4 d2 = src[tid + 512];
    float4 d3 = {};
    if (tid < 32) d3 = src[tid + 768];

    // ---- stage with XOR swizzle (scalar writes, dense & bijective -> ~2-way)
    {
        float vals[16] = {d0.x,d0.y,d0.z,d0.w, d1.x,d1.y,d1.z,d1.w,
                          d2.x,d2.y,d2.z,d2.w, d3.x,d3.y,d3.z,d3.w};
        #pragma unroll
        for (int r = 0; r < 4; ++r) {
            if (r == 3 && tid >= 32) break;
            const int f0 = (tid + 256 * r) * 4;
            #pragma unroll
            for (int k = 0; k < 4; ++k) {
                const int f = f0 + k;
                lx[f ^ ((f >> 5) & 3)] = vals[r * 4 + k];
            }
        }
    }
    __syncthreads();                 // lx + tq ready

    // ---- emit: per output quad, 2 b128 table reads + 4 swizzled gathers
    f32x4* dst = (f32x4*)(out + (size_t)row * ROW_);
    int w0 = (tid << 2) % 50u;       // (4*tid) % 50 ; even
    #pragma unroll
    for (int rep = 0; rep < 4; ++rep) {
        if (rep == 3 && tid >= 32) break;
        const int u  = tid + 256 * rep;      // output float4 index in row
        const int e0 = u * 4;                // output flat element index
        int wB = w0 + 2; if (wB >= V_) wB -= V_;
        const float4 tA = tq[w0 >> 1];
        const float4 tB = tq[wB >> 1];
        const int f0 = e0 + 0 + __float_as_int(tA.x);
        const int f1 = e0 + 1 + __float_as_int(tA.z);
        const int f2 = e0 + 2 + __float_as_int(tB.x);
        const int f3 = e0 + 3 + __float_as_int(tB.z);
        f32x4 o;
        o.x = lx[f0 ^ ((f0 >> 5) & 3)] * tA.y;
        o.y = lx[f1 ^ ((f1 >> 5) & 3)] * tA.w;
        o.z = lx[f2 ^ ((f2 >> 5) & 3)] * tB.y;
        o.w = lx[f3 ^ ((f3 >> 5) & 3)] * tB.w;
        __builtin_nontemporal_store(o, &dst[u]);
        w0 += 24; if (w0 >= V_) w0 -= V_;    // (w0 + 1024) % 50
    }
}

// ---------------------------------------------------------------------------
extern "C" void kernel_launch(void* const* d_in, const int* in_sizes, int n_in,
                              void* d_out, int out_size, void* d_ws, size_t ws_size,
                              hipStream_t stream) {
    const float* x  = (const float*)d_in[0];
    const float* W1 = (const float*)d_in[1];
    const float* b1 = (const float*)d_in[2];
    const float* W2 = (const float*)d_in[3];
    const float* b2 = (const float*)d_in[4];
    float* out = (float*)d_out;

    float* avg  = (float*)d_ws;            // NPC_ floats
    float* mx   = avg + NPC_;              // NPC_ floats
    float* gate = mx + NPC_;               // NPC_ floats

    reduce_kernel<<<NC_ / 4, 256, 0, stream>>>(x, avg, mx);
    mlp_kernel<<<N_ * NP_, 256, 0, stream>>>(avg, mx, W1, b1, W2, b2, gate);
    scale_kernel<<<NC_, 256, 0, stream>>>(x, gate, out);
}